// Round 1
// 72.921 us; speedup vs baseline: 1.0715x; 1.0715x over previous
//
#include <hip/hip_runtime.h>

#define IMG 100
#define OUTD 50
#define NPATCH 2500
#define NB 5
#define NGATE (NB * 8)  // per block: 4 u3 + 4 cu3

__device__ __forceinline__ float2 cmul(float2 a, float2 b) {
    return make_float2(a.x * b.x - a.y * b.y, a.x * b.y + a.y * b.x);
}
__device__ __forceinline__ float2 cadd(float2 a, float2 b) {
    return make_float2(a.x + b.x, a.y + b.y);
}

// ---------------------------------------------------------------------------
// Stage A (one workgroup, runs once): build the full-circuit unitary U (16x16)
// as a product of 5 per-block matrices (each simulated 8 gates deep on 16
// basis columns in parallel), then A_w(i,j) = sum_k sign_w(k) Re(conj(U_ki) U_kj).
// ws layout: ws[0..1023]  = A4[(i*16+j)*4 + w]
//            ws[1024..1031] = logits accumulator (zeroed here)
__global__ __launch_bounds__(512) void precompute_kernel(
    const float* __restrict__ u3p,
    const float* __restrict__ cu3p,
    float* __restrict__ ws)
{
    __shared__ float2 gm[NGATE][4];     // [gate][m00,m01,m10,m11]
    __shared__ float2 Bm[5][16][16];    // per-circuit-block unitaries
    __shared__ float2 P1[16][16];
    __shared__ float2 P2[16][16];
    __shared__ float2 P3[16][16];
    __shared__ float2 Um[16][16];

    const int tid = threadIdx.x;

    // --- gate matrices (40 lanes) ---
    if (tid < NGATE) {
        const int blk = tid >> 3;
        const int idx = tid & 7;
        const float* pp = (idx < 4) ? &u3p[(blk * 4 + idx) * 3]
                                    : &cu3p[(blk * 4 + (idx - 4)) * 3];
        const float th = pp[0], ph = pp[1], la = pp[2];
        float s, c, sl, cl, sp, cp, spl, cpl;
        sincosf(th * 0.5f, &s, &c);
        sincosf(la, &sl, &cl);
        sincosf(ph, &sp, &cp);
        sincosf(ph + la, &spl, &cpl);
        gm[tid][0] = make_float2(c, 0.0f);           // m00
        gm[tid][1] = make_float2(-cl * s, -sl * s);  // m01
        gm[tid][2] = make_float2(cp * s, sp * s);    // m10
        gm[tid][3] = make_float2(cpl * c, spl * c);  // m11
    }
    __syncthreads();

    // --- per-block unitaries: thread (blk,col) pushes basis column col
    //     through the 8 gates of circuit-block blk (compile-time masks) ---
    if (tid < 80) {
        const int blk = tid >> 4;
        const int col = tid & 15;
        float2 amp[16];
#pragma unroll
        for (int i = 0; i < 16; ++i)
            amp[i] = make_float2(i == col ? 1.0f : 0.0f, 0.0f);
#pragma unroll
        for (int g = 0; g < 8; ++g) {
            // g<4: U3 on wire g (no control). g>=4: CU3 ctrl=g-4, tgt=(g-3)&3.
            const int cmask = (g < 4) ? 0 : (8 >> (g - 4));
            const int tw    = (g < 4) ? g : ((g - 3) & 3);
            const int tmask = 8 >> tw;
            const float2 m0 = gm[blk * 8 + g][0];
            const float2 m1 = gm[blk * 8 + g][1];
            const float2 m2 = gm[blk * 8 + g][2];
            const float2 m3 = gm[blk * 8 + g][3];
#pragma unroll
            for (int i = 0; i < 16; ++i) {
                if ((i & tmask) == 0 && (i & cmask) == cmask) {
                    const float2 a0 = amp[i], a1 = amp[i + tmask];
                    amp[i]         = cadd(cmul(m0, a0), cmul(m1, a1));
                    amp[i + tmask] = cadd(cmul(m2, a0), cmul(m3, a1));
                }
            }
        }
#pragma unroll
        for (int k = 0; k < 16; ++k) Bm[blk][k][col] = amp[k];
    }
    __syncthreads();

    // --- U = B4*B3*B2*B1*B0, as (B4)*((B3*B2)*(B1*B0)) ---
    // round 1: P1 = B1*B0 (tid<256), P2 = B3*B2 (tid>=256) -- all 512 threads
    {
        const int e = tid & 255;
        const int i = e >> 4, j = e & 15;
        const float2 (*X)[16] = (tid & 256) ? Bm[3] : Bm[1];
        const float2 (*Y)[16] = (tid & 256) ? Bm[2] : Bm[0];
        float2 acc = make_float2(0.0f, 0.0f);
#pragma unroll
        for (int k = 0; k < 16; ++k) acc = cadd(acc, cmul(X[i][k], Y[k][j]));
        if (tid & 256) P2[i][j] = acc; else P1[i][j] = acc;
    }
    __syncthreads();
    if (tid < 256) {  // round 2: P3 = P2*P1
        const int i = tid >> 4, j = tid & 15;
        float2 acc = make_float2(0.0f, 0.0f);
#pragma unroll
        for (int k = 0; k < 16; ++k) acc = cadd(acc, cmul(P2[i][k], P1[k][j]));
        P3[i][j] = acc;
    }
    __syncthreads();
    if (tid < 256) {  // round 3: U = B4*P3
        const int i = tid >> 4, j = tid & 15;
        float2 acc = make_float2(0.0f, 0.0f);
#pragma unroll
        for (int k = 0; k < 16; ++k) acc = cadd(acc, cmul(Bm[4][i][k], P3[k][j]));
        Um[i][j] = acc;
    }
    __syncthreads();

    // --- A_w(i,j) = sum_k sign_w(k) * Re(conj(U_ki) * U_kj) ---
    if (tid < 256) {
        const int i = tid >> 4, j = tid & 15;
        float a0 = 0.f, a1 = 0.f, a2 = 0.f, a3 = 0.f;
#pragma unroll
        for (int k = 0; k < 16; ++k) {
            const float2 ui = Um[k][i];
            const float2 uj = Um[k][j];
            const float r = ui.x * uj.x + ui.y * uj.y;
            a0 += (k & 8) ? -r : r;   // wire 0 = MSB
            a1 += (k & 4) ? -r : r;
            a2 += (k & 2) ? -r : r;
            a3 += (k & 1) ? -r : r;
        }
        float* dst = &ws[tid << 2];   // layout [i][j][w]: conflict-free reads
        dst[0] = a0; dst[1] = a1; dst[2] = a2; dst[3] = a3;
    } else if (tid < 264) {
        ws[1024 + (tid - 256)] = 0.0f;  // zero logits accumulator
    }
}

// ---------------------------------------------------------------------------
// Stage B: one thread per (patch, wire). ez = s^T A_w s with s the real
// product state, then fused head partial: per-wave shfl reduce + atomicAdd.
__global__ __launch_bounds__(64) void patch_kernel(
    const float* __restrict__ img,
    const float* __restrict__ A4,
    const float* __restrict__ W,
    float* __restrict__ logits)
{
    __shared__ float As[1024];
    const int tid = threadIdx.x;
    {
        const float4* src = (const float4*)A4;
        float4* dst = (float4*)As;
#pragma unroll
        for (int r = 0; r < 4; ++r) dst[tid + 64 * r] = src[tid + 64 * r];
    }
    __syncthreads();

    const int w = tid & 3;
    const int p = blockIdx.x * 16 + (tid >> 2);
    float c0 = 0.0f, c1 = 0.0f;
    if (p < NPATCH) {
        const int rb = p / OUTD;
        const int cb = p - rb * OUTD;
        const int i0 = 2 * rb, j0 = 2 * cb;
        float v[4][2];
        sincosf(0.5f * img[i0 * IMG + j0],           &v[0][1], &v[0][0]);
        sincosf(0.5f * img[i0 * IMG + j0 + 1],       &v[1][1], &v[1][0]);
        sincosf(0.5f * img[(i0 + 1) * IMG + j0],     &v[2][1], &v[2][0]);
        sincosf(0.5f * img[(i0 + 1) * IMG + j0 + 1], &v[3][1], &v[3][0]);
        float t01[4], t23[4], s[16];
#pragma unroll
        for (int a = 0; a < 2; ++a)
#pragma unroll
            for (int bq = 0; bq < 2; ++bq) {
                t01[a * 2 + bq] = v[0][a] * v[1][bq];
                t23[a * 2 + bq] = v[2][a] * v[3][bq];
            }
#pragma unroll
        for (int i = 0; i < 16; ++i) s[i] = t01[i >> 2] * t23[i & 3];

        float acc = 0.0f;
#pragma unroll
        for (int i = 0; i < 16; ++i) {
            float inner = 0.0f;
#pragma unroll
            for (int j = 0; j < 16; ++j)
                inner = fmaf(As[((i * 16 + j) << 2) + w], s[j], inner);
            acc = fmaf(s[i], inner, acc);
        }
        // head: feat[q, j=cb*50+rb] = ez[p, q]
        const int jh = cb * OUTD + rb;
        c0 = acc * W[jh];
        c1 = acc * W[NPATCH + jh];
    }
    // sum the 16 lanes sharing each w (lane ids congruent mod 4)
#pragma unroll
    for (int off = 4; off < 64; off <<= 1) {
        c0 += __shfl_xor(c0, off, 64);
        c1 += __shfl_xor(c1, off, 64);
    }
    if (tid < 4) {
        atomicAdd(&logits[tid * 2 + 0], c0);
        atomicAdd(&logits[tid * 2 + 1], c1);
    }
}

// ---------------------------------------------------------------------------
__global__ __launch_bounds__(64) void finish_kernel(
    const float* __restrict__ logits,
    const float* __restrict__ b,
    float* __restrict__ out)
{
    if (threadIdx.x == 0) {
        const float b0 = b[0], b1 = b[1];
#pragma unroll
        for (int q = 0; q < 4; ++q) {
            const float l0 = logits[q * 2 + 0] + b0;
            const float l1 = logits[q * 2 + 1] + b1;
            const float m = fmaxf(l0, l1);
            const float lse = m + logf(expf(l0 - m) + expf(l1 - m));
            out[q * 2 + 0] = l0 - lse;
            out[q * 2 + 1] = l1 - lse;
        }
    }
}

extern "C" void kernel_launch(void* const* d_in, const int* in_sizes, int n_in,
                              void* d_out, int out_size, void* d_ws, size_t ws_size,
                              hipStream_t stream) {
    const float* img  = (const float*)d_in[0];
    const float* u3p  = (const float*)d_in[1];
    const float* cu3p = (const float*)d_in[2];
    const float* W    = (const float*)d_in[3];
    const float* b    = (const float*)d_in[4];
    float* out = (float*)d_out;
    float* ws  = (float*)d_ws;  // 1024 floats A4 + 8 floats logits

    precompute_kernel<<<1, 512, 0, stream>>>(u3p, cu3p, ws);
    patch_kernel<<<(NPATCH + 15) / 16, 64, 0, stream>>>(img, ws, W, ws + 1024);
    finish_kernel<<<1, 64, 0, stream>>>(ws + 1024, b, out);
}

// Round 2
// 70.881 us; speedup vs baseline: 1.1023x; 1.0288x over previous
//
#include <hip/hip_runtime.h>

#define IMG 100
#define OUTD 50
#define NPATCH 2500
#define NB 5
#define NGATE (NB * 8)  // per block: 4 u3 + 4 cu3
#define PBLK ((NPATCH + 15) / 16)  // 157 patch blocks

__device__ __forceinline__ float2 cmul(float2 a, float2 b) {
    return make_float2(a.x * b.x - a.y * b.y, a.x * b.y + a.y * b.x);
}
__device__ __forceinline__ float2 cadd(float2 a, float2 b) {
    return make_float2(a.x + b.x, a.y + b.y);
}

// ---------------------------------------------------------------------------
// Stage A (one workgroup, runs once): build the full-circuit unitary U (16x16)
// as a product of 5 per-block matrices (each simulated 8 gates deep on 16
// basis columns in parallel), then A_w(i,j) = sum_k sign_w(k) Re(conj(U_ki) U_kj).
// ws layout: ws[0..1023]            = A4[(i*16+j)*4 + w]
//            ws[1024..1024+PBLK*8)  = per-block logit partials
__global__ __launch_bounds__(512) void precompute_kernel(
    const float* __restrict__ u3p,
    const float* __restrict__ cu3p,
    float* __restrict__ ws)
{
    __shared__ float2 gm[NGATE][4];     // [gate][m00,m01,m10,m11]
    __shared__ float2 Bm[5][16][16];    // per-circuit-block unitaries
    __shared__ float2 P1[16][16];
    __shared__ float2 P2[16][16];
    __shared__ float2 P3[16][16];
    __shared__ float2 Um[16][16];

    const int tid = threadIdx.x;

    // --- gate matrices (40 lanes) ---
    if (tid < NGATE) {
        const int blk = tid >> 3;
        const int idx = tid & 7;
        const float* pp = (idx < 4) ? &u3p[(blk * 4 + idx) * 3]
                                    : &cu3p[(blk * 4 + (idx - 4)) * 3];
        const float th = pp[0], ph = pp[1], la = pp[2];
        float s, c, sl, cl, sp, cp, spl, cpl;
        sincosf(th * 0.5f, &s, &c);
        sincosf(la, &sl, &cl);
        sincosf(ph, &sp, &cp);
        sincosf(ph + la, &spl, &cpl);
        gm[tid][0] = make_float2(c, 0.0f);           // m00
        gm[tid][1] = make_float2(-cl * s, -sl * s);  // m01
        gm[tid][2] = make_float2(cp * s, sp * s);    // m10
        gm[tid][3] = make_float2(cpl * c, spl * c);  // m11
    }
    __syncthreads();

    // --- per-block unitaries: thread (blk,col) pushes basis column col
    //     through the 8 gates of circuit-block blk (compile-time masks) ---
    if (tid < 80) {
        const int blk = tid >> 4;
        const int col = tid & 15;
        float2 amp[16];
#pragma unroll
        for (int i = 0; i < 16; ++i)
            amp[i] = make_float2(i == col ? 1.0f : 0.0f, 0.0f);
#pragma unroll
        for (int g = 0; g < 8; ++g) {
            // g<4: U3 on wire g (no control). g>=4: CU3 ctrl=g-4, tgt=(g-3)&3.
            const int cmask = (g < 4) ? 0 : (8 >> (g - 4));
            const int tw    = (g < 4) ? g : ((g - 3) & 3);
            const int tmask = 8 >> tw;
            const float2 m0 = gm[blk * 8 + g][0];
            const float2 m1 = gm[blk * 8 + g][1];
            const float2 m2 = gm[blk * 8 + g][2];
            const float2 m3 = gm[blk * 8 + g][3];
#pragma unroll
            for (int i = 0; i < 16; ++i) {
                if ((i & tmask) == 0 && (i & cmask) == cmask) {
                    const float2 a0 = amp[i], a1 = amp[i + tmask];
                    amp[i]         = cadd(cmul(m0, a0), cmul(m1, a1));
                    amp[i + tmask] = cadd(cmul(m2, a0), cmul(m3, a1));
                }
            }
        }
#pragma unroll
        for (int k = 0; k < 16; ++k) Bm[blk][k][col] = amp[k];
    }
    __syncthreads();

    // --- U = B4*B3*B2*B1*B0, as (B4)*((B3*B2)*(B1*B0)) ---
    // round 1: P1 = B1*B0 (tid<256), P2 = B3*B2 (tid>=256) -- all 512 threads
    {
        const int e = tid & 255;
        const int i = e >> 4, j = e & 15;
        const float2 (*X)[16] = (tid & 256) ? Bm[3] : Bm[1];
        const float2 (*Y)[16] = (tid & 256) ? Bm[2] : Bm[0];
        float2 acc = make_float2(0.0f, 0.0f);
#pragma unroll
        for (int k = 0; k < 16; ++k) acc = cadd(acc, cmul(X[i][k], Y[k][j]));
        if (tid & 256) P2[i][j] = acc; else P1[i][j] = acc;
    }
    __syncthreads();
    if (tid < 256) {  // round 2: P3 = P2*P1
        const int i = tid >> 4, j = tid & 15;
        float2 acc = make_float2(0.0f, 0.0f);
#pragma unroll
        for (int k = 0; k < 16; ++k) acc = cadd(acc, cmul(P2[i][k], P1[k][j]));
        P3[i][j] = acc;
    }
    __syncthreads();
    if (tid < 256) {  // round 3: U = B4*P3
        const int i = tid >> 4, j = tid & 15;
        float2 acc = make_float2(0.0f, 0.0f);
#pragma unroll
        for (int k = 0; k < 16; ++k) acc = cadd(acc, cmul(Bm[4][i][k], P3[k][j]));
        Um[i][j] = acc;
    }
    __syncthreads();

    // --- A_w(i,j) = sum_k sign_w(k) * Re(conj(U_ki) * U_kj) ---
    if (tid < 256) {
        const int i = tid >> 4, j = tid & 15;
        float a0 = 0.f, a1 = 0.f, a2 = 0.f, a3 = 0.f;
#pragma unroll
        for (int k = 0; k < 16; ++k) {
            const float2 ui = Um[k][i];
            const float2 uj = Um[k][j];
            const float r = ui.x * uj.x + ui.y * uj.y;
            a0 += (k & 8) ? -r : r;   // wire 0 = MSB
            a1 += (k & 4) ? -r : r;
            a2 += (k & 2) ? -r : r;
            a3 += (k & 1) ? -r : r;
        }
        float* dst = &ws[tid << 2];   // layout [i][j][w]: conflict-free reads
        dst[0] = a0; dst[1] = a1; dst[2] = a2; dst[3] = a3;
    }
}

// ---------------------------------------------------------------------------
// Stage B: one thread per (patch, wire). ez = s^T A_w s with s the real
// product state, then fused head partial: per-wave shfl reduce, then a plain
// per-block store (NO atomics -- 157 blocks hammering one cacheline with
// device-scope atomicAdd serializes across XCDs).
__global__ __launch_bounds__(64) void patch_kernel(
    const float* __restrict__ img,
    const float* __restrict__ A4,
    const float* __restrict__ W,
    float* __restrict__ partials)
{
    __shared__ float As[1024];
    const int tid = threadIdx.x;
    {
        const float4* src = (const float4*)A4;
        float4* dst = (float4*)As;
#pragma unroll
        for (int r = 0; r < 4; ++r) dst[tid + 64 * r] = src[tid + 64 * r];
    }
    __syncthreads();

    const int w = tid & 3;
    const int p = blockIdx.x * 16 + (tid >> 2);
    float c0 = 0.0f, c1 = 0.0f;
    if (p < NPATCH) {
        const int rb = p / OUTD;
        const int cb = p - rb * OUTD;
        const int i0 = 2 * rb, j0 = 2 * cb;
        float v[4][2];
        sincosf(0.5f * img[i0 * IMG + j0],           &v[0][1], &v[0][0]);
        sincosf(0.5f * img[i0 * IMG + j0 + 1],       &v[1][1], &v[1][0]);
        sincosf(0.5f * img[(i0 + 1) * IMG + j0],     &v[2][1], &v[2][0]);
        sincosf(0.5f * img[(i0 + 1) * IMG + j0 + 1], &v[3][1], &v[3][0]);
        float t01[4], t23[4], s[16];
#pragma unroll
        for (int a = 0; a < 2; ++a)
#pragma unroll
            for (int bq = 0; bq < 2; ++bq) {
                t01[a * 2 + bq] = v[0][a] * v[1][bq];
                t23[a * 2 + bq] = v[2][a] * v[3][bq];
            }
#pragma unroll
        for (int i = 0; i < 16; ++i) s[i] = t01[i >> 2] * t23[i & 3];

        float acc = 0.0f;
#pragma unroll
        for (int i = 0; i < 16; ++i) {
            float inner = 0.0f;
#pragma unroll
            for (int j = 0; j < 16; ++j)
                inner = fmaf(As[((i * 16 + j) << 2) + w], s[j], inner);
            acc = fmaf(s[i], inner, acc);
        }
        // head: feat[q, j=cb*50+rb] = ez[p, q]
        const int jh = cb * OUTD + rb;
        c0 = acc * W[jh];
        c1 = acc * W[NPATCH + jh];
    }
    // sum the 16 lanes sharing each w (lane ids congruent mod 4)
#pragma unroll
    for (int off = 4; off < 64; off <<= 1) {
        c0 += __shfl_xor(c0, off, 64);
        c1 += __shfl_xor(c1, off, 64);
    }
    if (tid < 4) {
        partials[blockIdx.x * 8 + tid * 2 + 0] = c0;
        partials[blockIdx.x * 8 + tid * 2 + 1] = c1;
    }
}

// ---------------------------------------------------------------------------
// Single-wave reduction over PBLK*8 partials + bias + log_softmax.
__global__ __launch_bounds__(64) void finish_kernel(
    const float* __restrict__ partials,
    const float* __restrict__ b,
    float* __restrict__ out)
{
    const int tid = threadIdx.x;
    float acc[8] = {0.f, 0.f, 0.f, 0.f, 0.f, 0.f, 0.f, 0.f};
    for (int bi = tid; bi < PBLK; bi += 64) {
#pragma unroll
        for (int i = 0; i < 8; ++i) acc[i] += partials[bi * 8 + i];
    }
#pragma unroll
    for (int off = 1; off < 64; off <<= 1) {
#pragma unroll
        for (int i = 0; i < 8; ++i) acc[i] += __shfl_xor(acc[i], off, 64);
    }
    if (tid == 0) {
        const float b0 = b[0], b1 = b[1];
#pragma unroll
        for (int q = 0; q < 4; ++q) {
            const float l0 = acc[q * 2 + 0] + b0;
            const float l1 = acc[q * 2 + 1] + b1;
            const float m = fmaxf(l0, l1);
            const float lse = m + logf(expf(l0 - m) + expf(l1 - m));
            out[q * 2 + 0] = l0 - lse;
            out[q * 2 + 1] = l1 - lse;
        }
    }
}

extern "C" void kernel_launch(void* const* d_in, const int* in_sizes, int n_in,
                              void* d_out, int out_size, void* d_ws, size_t ws_size,
                              hipStream_t stream) {
    const float* img  = (const float*)d_in[0];
    const float* u3p  = (const float*)d_in[1];
    const float* cu3p = (const float*)d_in[2];
    const float* W    = (const float*)d_in[3];
    const float* b    = (const float*)d_in[4];
    float* out = (float*)d_out;
    float* ws  = (float*)d_ws;  // 1024 floats A4 + PBLK*8 partials

    precompute_kernel<<<1, 512, 0, stream>>>(u3p, cu3p, ws);
    patch_kernel<<<PBLK, 64, 0, stream>>>(img, ws, W, ws + 1024);
    finish_kernel<<<1, 64, 0, stream>>>(ws + 1024, b, out);
}